// Round 1
// baseline (683.714 us; speedup 1.0000x reference)
//
#include <hip/hip_runtime.h>
#include <hip/hip_bf16.h>

#define N 8192
#define H 256
constexpr float INV_TAU = 2.0f;  // 1/0.5

typedef __attribute__((ext_vector_type(8))) short bf16x8;   // 8 bf16 (4 VGPRs)
typedef __attribute__((ext_vector_type(4))) float f32x4;

// ---------------------------------------------------------------------------
// Kernel 1: z = elu(x @ W^T + b); zh = bf16(z / ||z||) per row.
// Block = 256 threads; wave w owns rows [blk*32 + w*8, +8), all 256 cols.
// x values are wave-uniform (lanes differ only in output col) -> SMEM loads.
// W rows come via per-lane vector loads (L1/L2-resident, 256 KB total).
__global__ __launch_bounds__(256) void proj_kernel(
    const float* __restrict__ v1, const float* __restrict__ v2,
    const float* __restrict__ W, const float* __restrict__ bias,
    __hip_bfloat16* __restrict__ zh1, __hip_bfloat16* __restrict__ zh2)
{
    const float* x = blockIdx.y ? v2 : v1;
    __hip_bfloat16* zh = blockIdx.y ? zh2 : zh1;
    int tid = threadIdx.x;
    int wave = __builtin_amdgcn_readfirstlane(tid >> 6);  // uniform for SMEM promo
    int hq = tid & 63;                                    // lane -> col group
    int row0 = blockIdx.x * 32 + wave * 8;

    float acc[8][4];
#pragma unroll
    for (int i = 0; i < 8; ++i)
#pragma unroll
        for (int c = 0; c < 4; ++c)
            acc[i][c] = bias[hq + 64 * c];

    const float* xrow = x + (long)row0 * H;
    for (int k = 0; k < H; k += 4) {
        float4 w[4];
#pragma unroll
        for (int c = 0; c < 4; ++c)
            w[c] = *(const float4*)&W[(hq + 64 * c) * H + k];
#pragma unroll
        for (int i = 0; i < 8; ++i) {
            float x0 = xrow[i * H + k + 0];
            float x1 = xrow[i * H + k + 1];
            float x2 = xrow[i * H + k + 2];
            float x3 = xrow[i * H + k + 3];
#pragma unroll
            for (int c = 0; c < 4; ++c) {
                acc[i][c] = fmaf(x0, w[c].x, acc[i][c]);
                acc[i][c] = fmaf(x1, w[c].y, acc[i][c]);
                acc[i][c] = fmaf(x2, w[c].z, acc[i][c]);
                acc[i][c] = fmaf(x3, w[c].w, acc[i][c]);
            }
        }
    }

#pragma unroll
    for (int i = 0; i < 8; ++i) {
        float ss = 0.f;
#pragma unroll
        for (int c = 0; c < 4; ++c) {
            float v = acc[i][c];
            v = v > 0.f ? v : (__expf(v) - 1.f);  // ELU, alpha=1
            acc[i][c] = v;
            ss = fmaf(v, v, ss);
        }
        // full-wave butterfly: every lane ends with the row's sum of squares
#pragma unroll
        for (int o = 1; o < 64; o <<= 1)
            ss += __shfl_xor(ss, o);
        float invn = rsqrtf(ss);
#pragma unroll
        for (int c = 0; c < 4; ++c)
            zh[(long)(row0 + i) * H + hq + 64 * c] =
                __float2bfloat16(acc[i][c] * invn);
    }
}

// ---------------------------------------------------------------------------
// Kernel 2: per 128x128 tile of cos = zh1 @ zh2^T (MFMA bf16), fused
// e = exp(2*cos); SP += e*pos; SN += e*neg; reduce -> binned atomics.
// 4 waves in 2x2 -> each wave owns a 64x64 quadrant = 4x4 MFMA tiles.
__global__ __launch_bounds__(256) void contrast_kernel(
    const __hip_bfloat16* __restrict__ zh1, const __hip_bfloat16* __restrict__ zh2,
    const float* __restrict__ pos, const float* __restrict__ neg,
    float* __restrict__ bins)
{
    int lane = threadIdx.x & 63;
    int wave = threadIdx.x >> 6;
    int wr = wave >> 1, wc = wave & 1;
    int r16 = lane & 15, quad = lane >> 4;
    long row0 = (long)blockIdx.x * 128 + wr * 64;
    long col0 = (long)blockIdx.y * 128 + wc * 64;

    f32x4 acc[4][4] = {};  // [mi][nj], zero-init

    // A/B fragment layout (verified): row = lane&15, k = (lane>>4)*8 + j
    const __hip_bfloat16* ap = zh1 + (row0 + r16) * H + quad * 8;
    const __hip_bfloat16* bp = zh2 + (col0 + r16) * H + quad * 8;
#pragma unroll
    for (int k = 0; k < H; k += 32) {
        bf16x8 a[4], b[4];
#pragma unroll
        for (int t = 0; t < 4; ++t) a[t] = *(const bf16x8*)(ap + t * 16 * H + k);
#pragma unroll
        for (int t = 0; t < 4; ++t) b[t] = *(const bf16x8*)(bp + t * 16 * H + k);
#pragma unroll
        for (int mi = 0; mi < 4; ++mi)
#pragma unroll
            for (int nj = 0; nj < 4; ++nj)
                acc[mi][nj] = __builtin_amdgcn_mfma_f32_16x16x32_bf16(
                    a[mi], b[nj], acc[mi][nj], 0, 0, 0);
    }

    // C/D layout (verified): col = lane&15, row = (lane>>4)*4 + reg
    float sp = 0.f, sn = 0.f;
#pragma unroll
    for (int mi = 0; mi < 4; ++mi) {
#pragma unroll
        for (int nj = 0; nj < 4; ++nj) {
            long r = row0 + mi * 16 + quad * 4;
            long c = col0 + nj * 16 + r16;
#pragma unroll
            for (int g = 0; g < 4; ++g) {
                float e = __expf(acc[mi][nj][g] * INV_TAU);
                long off = (r + g) * (long)N + c;  // 16 lanes -> 64B coalesced
                sp = fmaf(e, pos[off], sp);
                sn = fmaf(e, neg[off], sn);
            }
        }
    }

#pragma unroll
    for (int o = 32; o > 0; o >>= 1) {
        sp += __shfl_down(sp, o);
        sn += __shfl_down(sn, o);
    }
    __shared__ float wsum[4][2];
    if (lane == 0) { wsum[wave][0] = sp; wsum[wave][1] = sn; }
    __syncthreads();
    if (threadIdx.x == 0) {
        float bsp = wsum[0][0] + wsum[1][0] + wsum[2][0] + wsum[3][0];
        float bsn = wsum[0][1] + wsum[1][1] + wsum[2][1] + wsum[3][1];
        int bin = blockIdx.x & 63;  // x-fastest dispatch -> neighbors hit different bins
        atomicAdd(&bins[bin], bsp);
        atomicAdd(&bins[64 + bin], bsn);
    }
}

// ---------------------------------------------------------------------------
__global__ void final_kernel(const float* __restrict__ bins, float* __restrict__ out)
{
    int lane = threadIdx.x;  // 64 threads = 1 wave
    float sp = bins[lane], sn = bins[64 + lane];
#pragma unroll
    for (int o = 32; o > 0; o >>= 1) {
        sp += __shfl_down(sp, o);
        sn += __shfl_down(sn, o);
    }
    if (lane == 0) out[0] = -logf(sp / (sp + sn));
}

// ---------------------------------------------------------------------------
extern "C" void kernel_launch(void* const* d_in, const int* in_sizes, int n_in,
                              void* d_out, int out_size, void* d_ws, size_t ws_size,
                              hipStream_t stream)
{
    const float* v1   = (const float*)d_in[0];
    const float* v2   = (const float*)d_in[1];
    const float* pos  = (const float*)d_in[2];
    const float* neg  = (const float*)d_in[3];
    const float* W    = (const float*)d_in[4];
    const float* bias = (const float*)d_in[5];

    __hip_bfloat16* zh1 = (__hip_bfloat16*)d_ws;                    // 4 MB
    __hip_bfloat16* zh2 = zh1 + (size_t)N * H;                      // 4 MB
    float* bins = (float*)((char*)d_ws + 2ull * N * H * sizeof(__hip_bfloat16));

    hipMemsetAsync(bins, 0, 128 * sizeof(float), stream);  // ws is 0xAA-poisoned
    proj_kernel<<<dim3(N / 32, 2), 256, 0, stream>>>(v1, v2, W, bias, zh1, zh2);
    contrast_kernel<<<dim3(N / 128, N / 128), 256, 0, stream>>>(zh1, zh2, pos, neg, bins);
    final_kernel<<<1, 64, 0, stream>>>(bins, (float*)d_out);
}

// Round 2
// 640.684 us; speedup vs baseline: 1.0672x; 1.0672x over previous
//
#include <hip/hip_runtime.h>
#include <hip/hip_bf16.h>

#define N 8192
#define H 256

typedef __attribute__((ext_vector_type(8))) short bf16x8;   // 8 bf16 (4 VGPRs)
typedef __attribute__((ext_vector_type(4))) float f32x4;
typedef __attribute__((ext_vector_type(4))) _Float16 h4;

// ---------------------------------------------------------------------------
// Kernel 0: W (fp32, 256x256) -> bf16
__global__ __launch_bounds__(256) void convw_kernel(
    const float* __restrict__ W, __hip_bfloat16* __restrict__ Wb)
{
    int i = (blockIdx.x * 256 + threadIdx.x) * 4;   // 64 blocks cover 65536
    float4 w = *(const float4*)(W + i);
    __hip_bfloat16 o[4] = {__float2bfloat16(w.x), __float2bfloat16(w.y),
                           __float2bfloat16(w.z), __float2bfloat16(w.w)};
    *(short4*)(Wb + i) = *(short4*)o;
}

// ---------------------------------------------------------------------------
// Kernel 1 (MFMA): z = elu(x @ W^T + b); zh = bf16(z/||z||).
// 1 wave = 16 rows x 256 cols. A-frag: x loaded fp32, cvt to bf16 inline.
// B-frag: Wb row-major — B[n][k], n=lane&15, k=quad*8 (+ nt*16 rows of W).
__global__ __launch_bounds__(256) void proj_kernel(
    const float* __restrict__ v1, const float* __restrict__ v2,
    const __hip_bfloat16* __restrict__ Wb, const float* __restrict__ bias,
    __hip_bfloat16* __restrict__ zh1, __hip_bfloat16* __restrict__ zh2)
{
    const float* x = blockIdx.y ? v2 : v1;
    __hip_bfloat16* zh = blockIdx.y ? zh2 : zh1;
    int lane = threadIdx.x & 63, wave = threadIdx.x >> 6;
    int r16 = lane & 15, quad = lane >> 4;

    long arow = (long)blockIdx.x * 64 + wave * 16 + r16;
    const float* xr = x + arow * H + quad * 8;
    const __hip_bfloat16* wb = Wb + r16 * H + quad * 8;

    f32x4 acc[16] = {};
#pragma unroll
    for (int k8 = 0; k8 < 8; ++k8) {
        float4 xa = *(const float4*)(xr + k8 * 32);
        float4 xb = *(const float4*)(xr + k8 * 32 + 4);
        union { bf16x8 v; __hip_bfloat16 h[8]; } u;
        u.h[0] = __float2bfloat16(xa.x); u.h[1] = __float2bfloat16(xa.y);
        u.h[2] = __float2bfloat16(xa.z); u.h[3] = __float2bfloat16(xa.w);
        u.h[4] = __float2bfloat16(xb.x); u.h[5] = __float2bfloat16(xb.y);
        u.h[6] = __float2bfloat16(xb.z); u.h[7] = __float2bfloat16(xb.w);
#pragma unroll
        for (int nt = 0; nt < 16; ++nt) {
            bf16x8 bf = *(const bf16x8*)(wb + nt * 16 * H + k8 * 32);
            acc[nt] = __builtin_amdgcn_mfma_f32_16x16x32_bf16(u.v, bf, acc[nt], 0, 0, 0);
        }
    }

    // Epilogue. C/D: col = nt*16 + r16, row = wave*16 + quad*4 + g.
    float ss[4] = {};
#pragma unroll
    for (int nt = 0; nt < 16; ++nt) {
        float bc = bias[nt * 16 + r16];
#pragma unroll
        for (int g = 0; g < 4; ++g) {
            float v = acc[nt][g] + bc;
            v = v > 0.f ? v : (__expf(v) - 1.f);   // ELU alpha=1
            acc[nt][g] = v;
            ss[g] = fmaf(v, v, ss[g]);
        }
    }
    long crow0 = (long)blockIdx.x * 64 + wave * 16 + quad * 4;
#pragma unroll
    for (int g = 0; g < 4; ++g) {
        float s = ss[g];
#pragma unroll
        for (int o = 1; o < 16; o <<= 1) s += __shfl_xor(s, o);  // quad-local: row lives in 16 lanes
        float inv = rsqrtf(s);
#pragma unroll
        for (int nt = 0; nt < 16; ++nt)
            zh[(crow0 + g) * H + nt * 16 + r16] = __float2bfloat16(acc[nt][g] * inv);
    }
}

// ---------------------------------------------------------------------------
// Kernel 2: 128x128 tile: cos via MFMA -> e=exp(2c) -> LDS(fp16) ->
// coalesced float4 streaming of pos/neg with fused reduce -> binned atomics.
__global__ __launch_bounds__(256) void contrast_kernel(
    const __hip_bfloat16* __restrict__ zh1, const __hip_bfloat16* __restrict__ zh2,
    const float* __restrict__ pos, const float* __restrict__ neg,
    float* __restrict__ bins)
{
    __shared__ _Float16 elds[128][132];   // +4 pad: phase-B writes land 2 lanes/bank (free)
    int lane = threadIdx.x & 63;
    int wave = threadIdx.x >> 6;
    int wr = wave >> 1, wc = wave & 1;
    int r16 = lane & 15, quad = lane >> 4;
    long row0 = (long)blockIdx.x * 128 + wr * 64;
    long col0 = (long)blockIdx.y * 128 + wc * 64;

    f32x4 acc[4][4] = {};

    // A/B fragment: row = lane&15, k = (lane>>4)*8 + j
    const __hip_bfloat16* ap = zh1 + (row0 + r16) * H + quad * 8;
    const __hip_bfloat16* bp = zh2 + (col0 + r16) * H + quad * 8;
#pragma unroll
    for (int k = 0; k < H; k += 32) {
        bf16x8 a[4], b[4];
#pragma unroll
        for (int t = 0; t < 4; ++t) a[t] = *(const bf16x8*)(ap + t * 16 * H + k);
#pragma unroll
        for (int t = 0; t < 4; ++t) b[t] = *(const bf16x8*)(bp + t * 16 * H + k);
#pragma unroll
        for (int mi = 0; mi < 4; ++mi)
#pragma unroll
            for (int nj = 0; nj < 4; ++nj)
                acc[mi][nj] = __builtin_amdgcn_mfma_f32_16x16x32_bf16(
                    a[mi], b[nj], acc[mi][nj], 0, 0, 0);
    }

    // Phase B: e = exp(2*cos) -> LDS fp16. C/D: col=lane&15, row=quad*4+reg.
#pragma unroll
    for (int mi = 0; mi < 4; ++mi) {
        int lrow = wr * 64 + mi * 16 + quad * 4;
#pragma unroll
        for (int nj = 0; nj < 4; ++nj) {
            int lcol = wc * 64 + nj * 16 + r16;
#pragma unroll
            for (int g = 0; g < 4; ++g)
                elds[lrow + g][lcol] = (_Float16)__expf(acc[mi][nj][g] * 2.0f);
        }
    }
    __syncthreads();

    // Phase C: fully-coalesced float4 streaming, 16-deep load batches.
    const float* pb = pos + ((long)blockIdx.x * 128) * N + (long)blockIdx.y * 128;
    const float* nb = neg + ((long)blockIdx.x * 128) * N + (long)blockIdx.y * 128;
    float sp = 0.f, sn = 0.f;
#pragma unroll
    for (int half = 0; half < 2; ++half) {
        float4 pv[8], nv[8];
#pragma unroll
        for (int it = 0; it < 8; ++it) {
            int idx = threadIdx.x + (half * 8 + it) * 256;
            long r = idx >> 5;
            int c = (idx & 31) * 4;
            pv[it] = *(const float4*)(pb + r * N + c);
            nv[it] = *(const float4*)(nb + r * N + c);
        }
#pragma unroll
        for (int it = 0; it < 8; ++it) {
            int idx = threadIdx.x + (half * 8 + it) * 256;
            int r = idx >> 5;
            int c = (idx & 31) * 4;
            h4 e = *(const h4*)&elds[r][c];
            sp = fmaf((float)e.x, pv[it].x, sp);
            sp = fmaf((float)e.y, pv[it].y, sp);
            sp = fmaf((float)e.z, pv[it].z, sp);
            sp = fmaf((float)e.w, pv[it].w, sp);
            sn = fmaf((float)e.x, nv[it].x, sn);
            sn = fmaf((float)e.y, nv[it].y, sn);
            sn = fmaf((float)e.z, nv[it].z, sn);
            sn = fmaf((float)e.w, nv[it].w, sn);
        }
    }

#pragma unroll
    for (int o = 32; o > 0; o >>= 1) {
        sp += __shfl_down(sp, o);
        sn += __shfl_down(sn, o);
    }
    __shared__ float wsum[4][2];
    if (lane == 0) { wsum[wave][0] = sp; wsum[wave][1] = sn; }
    __syncthreads();
    if (threadIdx.x == 0) {
        float bsp = wsum[0][0] + wsum[1][0] + wsum[2][0] + wsum[3][0];
        float bsn = wsum[0][1] + wsum[1][1] + wsum[2][1] + wsum[3][1];
        int bin = blockIdx.x & 63;
        atomicAdd(&bins[bin], bsp);
        atomicAdd(&bins[64 + bin], bsn);
    }
}

// ---------------------------------------------------------------------------
__global__ void final_kernel(const float* __restrict__ bins, float* __restrict__ out)
{
    int lane = threadIdx.x;  // 64 threads = 1 wave
    float sp = bins[lane], sn = bins[64 + lane];
#pragma unroll
    for (int o = 32; o > 0; o >>= 1) {
        sp += __shfl_down(sp, o);
        sn += __shfl_down(sn, o);
    }
    if (lane == 0) out[0] = -logf(sp / (sp + sn));
}

// ---------------------------------------------------------------------------
extern "C" void kernel_launch(void* const* d_in, const int* in_sizes, int n_in,
                              void* d_out, int out_size, void* d_ws, size_t ws_size,
                              hipStream_t stream)
{
    const float* v1   = (const float*)d_in[0];
    const float* v2   = (const float*)d_in[1];
    const float* pos  = (const float*)d_in[2];
    const float* neg  = (const float*)d_in[3];
    const float* W    = (const float*)d_in[4];
    const float* bias = (const float*)d_in[5];

    __hip_bfloat16* zh1 = (__hip_bfloat16*)d_ws;                    // 4 MB
    __hip_bfloat16* zh2 = zh1 + (size_t)N * H;                      // 4 MB
    char* p8 = (char*)d_ws + 2ull * N * H * sizeof(__hip_bfloat16);
    __hip_bfloat16* Wb = (__hip_bfloat16*)p8;                       // 128 KB
    float* bins = (float*)(p8 + (size_t)H * H * sizeof(__hip_bfloat16));

    hipMemsetAsync(bins, 0, 128 * sizeof(float), stream);
    convw_kernel<<<64, 256, 0, stream>>>(W, Wb);
    proj_kernel<<<dim3(N / 64, 2), 256, 0, stream>>>(v1, v2, Wb, bias, zh1, zh2);
    contrast_kernel<<<dim3(N / 128, N / 128), 256, 0, stream>>>(zh1, zh2, pos, neg, bins);
    final_kernel<<<1, 64, 0, stream>>>(bins, (float*)d_out);
}